// Round 1
// baseline (2022.327 us; speedup 1.0000x reference)
//
#include <hip/hip_runtime.h>
#include <hip/hip_bf16.h>
#include <stdint.h>

#define NCELL 40000
#define EUE   200000
#define EDE   200000
#define EBE   120000
#define NBC   60000
#define NM    ((size_t)NCELL * 256)

typedef __attribute__((ext_vector_type(8))) short bf16x8;
typedef __attribute__((ext_vector_type(4))) float f32x4;

__device__ __forceinline__ uint16_t f2bf(float f) {
  union { float f; uint32_t u; } v; v.f = f;
  uint32_t u = v.u;
  u += 0x7fffu + ((u >> 16) & 1u);   // round-to-nearest-even
  return (uint16_t)(u >> 16);
}

// ---------------- weight transpose + fp32->bf16 convert ----------------
// src: K x 256 fp32 row-major  ->  dst: 256 x K bf16 row-major (B^T form)
struct WArgs {
  const float* src[11];
  uint16_t*    dst[11];
  int          K[11];
};

__global__ void k_wconv(WArgs a) {
  int m = blockIdx.z;
  int K = a.K[m];
  int k0 = blockIdx.x * 32;
  if (k0 >= K) return;
  int n0 = blockIdx.y * 32;
  __shared__ float t[32][33];
  int tx = threadIdx.x, ty = threadIdx.y;
  const float* src = a.src[m];
  for (int i = ty; i < 32; i += 8)
    t[i][tx] = src[(size_t)(k0 + i) * 256 + n0 + tx];
  __syncthreads();
  uint16_t* dst = a.dst[m];
  for (int i = ty; i < 32; i += 8)
    dst[(size_t)(n0 + i) * K + k0 + tx] = f2bf(t[tx][i]);
}

// ---------------- init: acc_t = (1+eps_t) * x ----------------
__global__ void k_init(const float* __restrict__ x, const float* e1, const float* e2,
                       const float* e3, float* __restrict__ au, float* __restrict__ ad,
                       float* __restrict__ ab) {
  size_t i = (size_t)blockIdx.x * 256 + threadIdx.x;
  float s1 = 1.f + *e1, s2 = 1.f + *e2, s3 = 1.f + *e3;
  float4 v = ((const float4*)x)[i];
  ((float4*)au)[i] = make_float4(v.x * s1, v.y * s1, v.z * s1, v.w * s1);
  ((float4*)ad)[i] = make_float4(v.x * s2, v.y * s2, v.z * s2, v.w * s2);
  ((float4*)ab)[i] = make_float4(v.x * s3, v.y * s3, v.z * s3, v.w * s3);
}

// ---------------- boundary scatter: acc_b[tgt] += battr[src] ----------------
__global__ void k_bscatter(const float* __restrict__ battr, const int* __restrict__ bsrc,
                           const int* __restrict__ btgt, float* __restrict__ accb) {
  int e = blockIdx.x;
  int s = bsrc[e], t = btgt[e];
  int c = threadIdx.x * 4;
  float4 v = *(const float4*)(battr + (size_t)s * 256 + c);
  float* d = accb + (size_t)t * 256 + c;
  atomicAdd(d + 0, v.x); atomicAdd(d + 1, v.y);
  atomicAdd(d + 2, v.z); atomicAdd(d + 3, v.w);
}

// ---------------- per-column sums for BN (s1[256], s2[256]) ----------------
__global__ void k_stats(const float* __restrict__ Y, float* __restrict__ s12) {
  int c = threadIdx.x;
  int r0 = blockIdx.x * 250;
  float s1 = 0.f, s2 = 0.f;
  for (int r = 0; r < 250; r++) {
    float v = Y[(size_t)(r0 + r) * 256 + c];
    s1 += v; s2 += v * v;
  }
  atomicAdd(&s12[c], s1);
  atomicAdd(&s12[256 + c], s2);
}

// ---------------- BN scale/shift + ReLU, write with stride ldo ----------------
__global__ void k_bnrelu(const float* __restrict__ Y, const float* __restrict__ s12,
                         const float* __restrict__ g, const float* __restrict__ cb,
                         float* __restrict__ out, int ldo) {
  int i = blockIdx.x * 256 + threadIdx.x;
  int c = (i & 63) * 4;
  size_t row = (size_t)(i >> 6);
  const float invN = 1.f / (float)NCELL;
  float4 v = *(const float4*)(Y + row * 256 + c);
  float vv[4] = {v.x, v.y, v.z, v.w};
  float o[4];
#pragma unroll
  for (int k = 0; k < 4; k++) {
    float mean = s12[c + k] * invN;
    float var  = s12[256 + c + k] * invN - mean * mean;
    float sc = g[c + k] * rsqrtf(var + 1e-5f);
    float sh = cb[c + k] - mean * sc;
    o[k] = fmaxf(vv[k] * sc + sh, 0.f);
  }
  *(float4*)(out + row * (size_t)ldo + c) = make_float4(o[0], o[1], o[2], o[3]);
}

// ---------------- bf16 MFMA GEMM: C(MxN=256) = A(fp32,MxK) * Bt(bf16,[256][K]) ----------------
// MODE 0: C[row][col] = acc + bias[col]  (bias nullable)
// MODE 1: v = relu(acc + XT[src[row]][col] + bias[col]); atomicAdd(accOut[dst[row]][col], v)
template <int MODE>
__global__ __launch_bounds__(256)
void k_gemm(const float* __restrict__ A, int lda, const uint16_t* __restrict__ Bt, int K,
            const float* __restrict__ bias, float* __restrict__ C,
            const float* __restrict__ XT, const int* __restrict__ srcIdx,
            const int* __restrict__ dstIdx, float* __restrict__ accOut, int M) {
  __shared__ uint16_t Al[128 * 32];
  __shared__ uint16_t Bl[128 * 32];
  const int tid = threadIdx.x;
  const int m0 = blockIdx.x * 128;
  const int n0 = blockIdx.y * 128;
  const int lane = tid & 63;
  const int wave = tid >> 6;
  const int wr = (wave >> 1) * 64;
  const int wc = (wave & 1) * 64;
  const int lm = lane & 15;
  const int lq = lane >> 4;

  f32x4 acc[4][4];
#pragma unroll
  for (int i = 0; i < 4; i++)
#pragma unroll
    for (int j = 0; j < 4; j++)
      acc[i][j] = f32x4{0.f, 0.f, 0.f, 0.f};

  const int arow = tid >> 3;        // 0..31
  const int acol = (tid & 7) * 4;   // 0,4,..,28

  for (int kt = 0; kt < K; kt += 32) {
    // stage A (fp32 -> bf16), 128 x 32
#pragma unroll
    for (int rr = 0; rr < 4; rr++) {
      int r = arow + rr * 32;
      int gr = m0 + r;
      float4 v = make_float4(0.f, 0.f, 0.f, 0.f);
      if (gr < M) v = *(const float4*)(A + (size_t)gr * lda + kt + acol);
      union { uint16_t h[4]; uint2 u; } p;
      p.h[0] = f2bf(v.x); p.h[1] = f2bf(v.y); p.h[2] = f2bf(v.z); p.h[3] = f2bf(v.w);
      *(uint2*)(Al + r * 32 + acol) = p.u;
    }
    // stage B (already bf16, B^T layout [n][k]) : tile 128 x 32
#pragma unroll
    for (int ss = 0; ss < 2; ss++) {
      int j = tid + ss * 256;
      int row = j >> 2, kp = (j & 3) * 8;
      uint4 bv = *(const uint4*)(Bt + (size_t)(n0 + row) * K + kt + kp);
      *(uint4*)(Bl + row * 32 + kp) = bv;
    }
    __syncthreads();
    bf16x8 af[4], bfr[4];
#pragma unroll
    for (int i = 0; i < 4; i++)
      af[i] = *(const bf16x8*)(Al + (wr + 16 * i + lm) * 32 + lq * 8);
#pragma unroll
    for (int j = 0; j < 4; j++)
      bfr[j] = *(const bf16x8*)(Bl + (wc + 16 * j + lm) * 32 + lq * 8);
#pragma unroll
    for (int i = 0; i < 4; i++)
#pragma unroll
      for (int j = 0; j < 4; j++)
        acc[i][j] = __builtin_amdgcn_mfma_f32_16x16x32_bf16(af[i], bfr[j], acc[i][j], 0, 0, 0);
    __syncthreads();
  }

  const int cb0 = n0 + wc + lm;
  if (MODE == 0) {
    float bj[4];
#pragma unroll
    for (int j = 0; j < 4; j++) bj[j] = bias ? bias[cb0 + 16 * j] : 0.f;
#pragma unroll
    for (int i = 0; i < 4; i++) {
      int rbase = m0 + wr + 16 * i + lq * 4;
#pragma unroll
      for (int r = 0; r < 4; r++) {
        int row = rbase + r;
        if (row < M) {
#pragma unroll
          for (int j = 0; j < 4; j++)
            C[(size_t)row * 256 + cb0 + 16 * j] = acc[i][j][r] + bj[j];
        }
      }
    }
  } else {
    float bj[4];
#pragma unroll
    for (int j = 0; j < 4; j++) bj[j] = bias[cb0 + 16 * j];
#pragma unroll
    for (int i = 0; i < 4; i++) {
      int rbase = m0 + wr + 16 * i + lq * 4;
#pragma unroll
      for (int r = 0; r < 4; r++) {
        int row = rbase + r;
        if (row < M) {
          int s = srcIdx[row], t = dstIdx[row];
          const float* xr = XT + (size_t)s * 256;
          float* orow = accOut + (size_t)t * 256;
#pragma unroll
          for (int j = 0; j < 4; j++) {
            float v = acc[i][j][r] + xr[cb0 + 16 * j] + bj[j];
            v = fmaxf(v, 0.f);
            atomicAdd(&orow[cb0 + 16 * j], v);
          }
        }
      }
    }
  }
}

// ---------------- launch ----------------
extern "C" void kernel_launch(void* const* d_in, const int* in_sizes, int n_in,
                              void* d_out, int out_size, void* d_ws, size_t ws_size,
                              hipStream_t stream) {
  const float* x    = (const float*)d_in[0];
  const float* upA  = (const float*)d_in[1];
  const float* dnA  = (const float*)d_in[2];
  const float* bA   = (const float*)d_in[3];
  const float* Wmu  = (const float*)d_in[4];
  const float* bmu  = (const float*)d_in[5];
  const float* Wmd  = (const float*)d_in[6];
  const float* bmd  = (const float*)d_in[7];
  const float* W1[3] = {(const float*)d_in[8],  (const float*)d_in[16], (const float*)d_in[24]};
  const float* b1[3] = {(const float*)d_in[9],  (const float*)d_in[17], (const float*)d_in[25]};
  const float* g1[3] = {(const float*)d_in[10], (const float*)d_in[18], (const float*)d_in[26]};
  const float* c1[3] = {(const float*)d_in[11], (const float*)d_in[19], (const float*)d_in[27]};
  const float* W2[3] = {(const float*)d_in[12], (const float*)d_in[20], (const float*)d_in[28]};
  const float* b2[3] = {(const float*)d_in[13], (const float*)d_in[21], (const float*)d_in[29]};
  const float* g2[3] = {(const float*)d_in[14], (const float*)d_in[22], (const float*)d_in[30]};
  const float* c2[3] = {(const float*)d_in[15], (const float*)d_in[23], (const float*)d_in[31]};
  const float* Wc   = (const float*)d_in[32];
  const float* bc   = (const float*)d_in[33];
  const float* gc   = (const float*)d_in[34];
  const float* cc   = (const float*)d_in[35];
  const float* e1   = (const float*)d_in[36];
  const float* e2   = (const float*)d_in[37];
  const float* e3   = (const float*)d_in[38];
  const int* upI = (const int*)d_in[39];
  const int* dnI = (const int*)d_in[40];
  const int* bI  = (const int*)d_in[41];

  // workspace layout
  float* base = (float*)d_ws;
  size_t o = 0;
  float* XU     = base + o; o += NM;
  float* XD     = base + o; o += NM;
  float* ACC0   = base + o; o += NM;
  float* ACC1   = base + o; o += NM;
  float* ACC2   = base + o; o += NM;
  float* Y      = base + o; o += NM;
  float* Z      = base + o; o += NM;
  float* CAT    = base + o; o += (size_t)NCELL * 768;
  float* STATS  = base + o; o += 7 * 512;
  uint16_t* wb  = (uint16_t*)(base + o);
  uint16_t* WmuAt = wb;
  uint16_t* WmuBt = wb + 1 * 65536;
  uint16_t* WmdAt = wb + 2 * 65536;
  uint16_t* WmdBt = wb + 3 * 65536;
  uint16_t* W1t[3] = {wb + 4 * 65536, wb + 5 * 65536, wb + 6 * 65536};
  uint16_t* W2t[3] = {wb + 7 * 65536, wb + 8 * 65536, wb + 9 * 65536};
  uint16_t* Wct    = wb + 10 * 65536;   // 256 x 768

  float* ACCs[3] = {ACC0, ACC1, ACC2};

  hipMemsetAsync(STATS, 0, 7 * 512 * sizeof(float), stream);

  // convert + transpose all weights to bf16 B^T form
  WArgs wa;
  wa.src[0] = Wmu;               wa.dst[0] = WmuAt;  wa.K[0] = 256;
  wa.src[1] = Wmu + 256 * 256;   wa.dst[1] = WmuBt;  wa.K[1] = 256;
  wa.src[2] = Wmd;               wa.dst[2] = WmdAt;  wa.K[2] = 256;
  wa.src[3] = Wmd + 256 * 256;   wa.dst[3] = WmdBt;  wa.K[3] = 256;
  for (int t = 0; t < 3; t++) {
    wa.src[4 + 2 * t] = W1[t];   wa.dst[4 + 2 * t] = W1t[t]; wa.K[4 + 2 * t] = 256;
    wa.src[5 + 2 * t] = W2[t];   wa.dst[5 + 2 * t] = W2t[t]; wa.K[5 + 2 * t] = 256;
  }
  wa.src[10] = Wc; wa.dst[10] = Wct; wa.K[10] = 768;
  k_wconv<<<dim3(24, 8, 11), dim3(32, 8), 0, stream>>>(wa);

  // acc_t = (1+eps_t)*x
  k_init<<<10000, 256, 0, stream>>>(x, e1, e2, e3, ACC0, ACC1, ACC2);

  const dim3 gN((NCELL + 127) / 128, 2);
  const dim3 gE((EUE + 127) / 128, 2);

  // XU = x @ Wmu[:256],  XD = x @ Wmd[:256]
  k_gemm<0><<<gN, 256, 0, stream>>>(x, 256, WmuAt, 256, nullptr, XU,
                                    nullptr, nullptr, nullptr, nullptr, NCELL);
  k_gemm<0><<<gN, 256, 0, stream>>>(x, 256, WmdAt, 256, nullptr, XD,
                                    nullptr, nullptr, nullptr, nullptr, NCELL);

  // edge GEMMs with fused relu + scatter-add
  k_gemm<1><<<gE, 256, 0, stream>>>(upA, 256, WmuBt, 256, bmu, nullptr,
                                    XU, upI, upI + EUE, ACC0, EUE);
  k_gemm<1><<<gE, 256, 0, stream>>>(dnA, 256, WmdBt, 256, bmd, nullptr,
                                    XD, dnI, dnI + EDE, ACC1, EDE);

  // boundary scatter (identity messages)
  k_bscatter<<<EBE, 64, 0, stream>>>(bA, bI, bI + EBE, ACC2);

  // three MLP branches
  for (int t = 0; t < 3; t++) {
    float* S1 = STATS + 512 * (2 * t);
    float* S2 = STATS + 512 * (2 * t + 1);
    k_gemm<0><<<gN, 256, 0, stream>>>(ACCs[t], 256, W1t[t], 256, b1[t], Y,
                                      nullptr, nullptr, nullptr, nullptr, NCELL);
    k_stats<<<160, 256, 0, stream>>>(Y, S1);
    k_bnrelu<<<10000, 256, 0, stream>>>(Y, S1, g1[t], c1[t], Z, 256);
    k_gemm<0><<<gN, 256, 0, stream>>>(Z, 256, W2t[t], 256, b2[t], Y,
                                      nullptr, nullptr, nullptr, nullptr, NCELL);
    k_stats<<<160, 256, 0, stream>>>(Y, S2);
    k_bnrelu<<<10000, 256, 0, stream>>>(Y, S2, g2[t], c2[t], CAT + 256 * t, 768);
  }

  // final combine: Yc = CAT @ Wc + bc ; out = relu(BN(Yc))
  float* SC = STATS + 512 * 6;
  k_gemm<0><<<gN, 256, 0, stream>>>(CAT, 768, Wct, 768, bc, Y,
                                    nullptr, nullptr, nullptr, nullptr, NCELL);
  k_stats<<<160, 256, 0, stream>>>(Y, SC);
  k_bnrelu<<<10000, 256, 0, stream>>>(Y, SC, gc, cc, (float*)d_out, 256);
}

// Round 2
// 1612.350 us; speedup vs baseline: 1.2543x; 1.2543x over previous
//
#include <hip/hip_runtime.h>
#include <hip/hip_bf16.h>
#include <stdint.h>

#define NCELL 40000
#define EUE   200000
#define EDE   200000
#define EBE   120000
#define NM    ((size_t)NCELL * 256)

typedef __attribute__((ext_vector_type(8))) short bf16x8;
typedef __attribute__((ext_vector_type(4))) float f32x4;

__device__ __forceinline__ uint16_t f2bf(float f) {
  union { float f; uint32_t u; } v; v.f = f;
  uint32_t u = v.u;
  u += 0x7fffu + ((u >> 16) & 1u);   // round-to-nearest-even
  return (uint16_t)(u >> 16);
}

// ---------------- weight transpose + fp32->bf16 convert ----------------
struct WArgs {
  const float* src[11];
  uint16_t*    dst[11];
  int          K[11];
};

__global__ void k_wconv(WArgs a) {
  int m = blockIdx.z;
  int K = a.K[m];
  int k0 = blockIdx.x * 32;
  if (k0 >= K) return;
  int n0 = blockIdx.y * 32;
  __shared__ float t[32][33];
  int tx = threadIdx.x, ty = threadIdx.y;
  const float* src = a.src[m];
  for (int i = ty; i < 32; i += 8)
    t[i][tx] = src[(size_t)(k0 + i) * 256 + n0 + tx];
  __syncthreads();
  uint16_t* dst = a.dst[m];
  for (int i = ty; i < 32; i += 8)
    dst[(size_t)(n0 + i) * K + k0 + tx] = f2bf(t[tx][i]);
}

// ---------------- CSR build: count -> scan -> fill ----------------
__global__ void k_count(const int* __restrict__ tgt, int* __restrict__ cnt, int E) {
  int i = blockIdx.x * 256 + threadIdx.x;
  if (i < E) atomicAdd(&cnt[tgt[i]], 1);
}

struct ScanArgs { const int* cnt[3]; int* offs[3]; int* head[3]; };

__global__ void k_scan(ScanArgs a) {
  int s = blockIdx.x;
  const int n = NCELL;
  const int* cnt = a.cnt[s];
  int* offs = a.offs[s];
  int* head = a.head[s];
  __shared__ int buf[1024];
  __shared__ int carry;
  int tid = threadIdx.x;
  if (tid == 0) carry = 0;
  __syncthreads();
  for (int base = 0; base < n; base += 1024) {
    int i = base + tid;
    int v = (i < n) ? cnt[i] : 0;
    buf[tid] = v;
    __syncthreads();
    for (int d = 1; d < 1024; d <<= 1) {
      int t = (tid >= d) ? buf[tid - d] : 0;
      __syncthreads();
      buf[tid] += t;
      __syncthreads();
    }
    int excl = carry + buf[tid] - v;
    if (i < n) { offs[i] = excl; head[i] = excl; }
    __syncthreads();
    if (tid == 1023) carry += buf[1023];
    __syncthreads();
  }
  if (tid == 0) offs[n] = carry;
}

__global__ void k_fill(const int* __restrict__ src, const int* __restrict__ tgt,
                       int* __restrict__ head, int* __restrict__ perm,
                       int* __restrict__ psrc, int E) {
  int e = blockIdx.x * 256 + threadIdx.x;
  if (e < E) {
    int p = atomicAdd(&head[tgt[e]], 1);
    perm[p] = e;
    psrc[p] = src[e];
  }
}

// ---------------- segment sum: out[t] = (1+eps)*x[t] + sum_{j in seg} MSG[j] ----------------
__global__ void k_segsum(const float* __restrict__ MSG, const int* __restrict__ offs,
                         const float* __restrict__ x, const float* __restrict__ eps,
                         float* __restrict__ out) {
  int t = blockIdx.x;
  int c = threadIdx.x * 4;
  int s = offs[t], e = offs[t + 1];
  float sE = 1.f + *eps;
  float4 xa = *(const float4*)(x + (size_t)t * 256 + c);
  float a0 = xa.x * sE, a1 = xa.y * sE, a2 = xa.z * sE, a3 = xa.w * sE;
  for (int j = s; j < e; j++) {
    float4 v = *(const float4*)(MSG + (size_t)j * 256 + c);
    a0 += v.x; a1 += v.y; a2 += v.z; a3 += v.w;
  }
  *(float4*)(out + (size_t)t * 256 + c) = make_float4(a0, a1, a2, a3);
}

// ---------------- boundary gather: out[t] = (1+eps)*x[t] + sum battr[psrc[j]] ----------------
__global__ void k_bgather(const float* __restrict__ battr, const int* __restrict__ offs,
                          const int* __restrict__ psrc, const float* __restrict__ x,
                          const float* __restrict__ eps, float* __restrict__ out) {
  int t = blockIdx.x;
  int c = threadIdx.x * 4;
  int s = offs[t], e = offs[t + 1];
  float sE = 1.f + *eps;
  float4 xa = *(const float4*)(x + (size_t)t * 256 + c);
  float a0 = xa.x * sE, a1 = xa.y * sE, a2 = xa.z * sE, a3 = xa.w * sE;
  for (int j = s; j < e; j++) {
    int sr = psrc[j];
    float4 v = *(const float4*)(battr + (size_t)sr * 256 + c);
    a0 += v.x; a1 += v.y; a2 += v.z; a3 += v.w;
  }
  *(float4*)(out + (size_t)t * 256 + c) = make_float4(a0, a1, a2, a3);
}

// ---------------- BN scale/shift + ReLU, write with stride ldo ----------------
__global__ void k_bnrelu(const float* __restrict__ Y, const float* __restrict__ s12,
                         const float* __restrict__ g, const float* __restrict__ cb,
                         float* __restrict__ out, int ldo) {
  int i = blockIdx.x * 256 + threadIdx.x;
  int c = (i & 63) * 4;
  size_t row = (size_t)(i >> 6);
  const float invN = 1.f / (float)NCELL;
  float4 v = *(const float4*)(Y + row * 256 + c);
  float vv[4] = {v.x, v.y, v.z, v.w};
  float o[4];
#pragma unroll
  for (int k = 0; k < 4; k++) {
    float mean = s12[c + k] * invN;
    float var  = s12[256 + c + k] * invN - mean * mean;
    float sc = g[c + k] * rsqrtf(var + 1e-5f);
    float sh = cb[c + k] - mean * sc;
    o[k] = fmaxf(vv[k] * sc + sh, 0.f);
  }
  *(float4*)(out + row * (size_t)ldo + c) = make_float4(o[0], o[1], o[2], o[3]);
}

// ---------------- bf16 MFMA GEMM ----------------
// MODE 0: dense A; C[row][col] = acc + bias[col]; optional fused column stats (sum, sumsq)
// MODE 1: A rows gathered via perm; C[row][col] = relu(acc + XT[psrc[row]][col] + bias[col])
//         (C written contiguously in CSR order; no atomics)
template <int MODE>
__global__ __launch_bounds__(256)
void k_gemm(const float* __restrict__ A, int lda, const uint16_t* __restrict__ Bt, int K,
            const float* __restrict__ bias, float* __restrict__ C, float* __restrict__ stats,
            const int* __restrict__ perm, const int* __restrict__ psrc,
            const float* __restrict__ XT, int M) {
  __shared__ uint16_t Al[128 * 32];
  __shared__ uint16_t Bl[128 * 32];
  const int tid = threadIdx.x;
  const int m0 = blockIdx.x * 128;
  const int n0 = blockIdx.y * 128;
  const int lane = tid & 63;
  const int wave = tid >> 6;
  const int wr = (wave >> 1) * 64;
  const int wc = (wave & 1) * 64;
  const int lm = lane & 15;
  const int lq = lane >> 4;

  f32x4 acc[4][4];
#pragma unroll
  for (int i = 0; i < 4; i++)
#pragma unroll
    for (int j = 0; j < 4; j++)
      acc[i][j] = f32x4{0.f, 0.f, 0.f, 0.f};

  const int arow = tid >> 3;        // 0..31
  const int acol = (tid & 7) * 4;   // 0,4,..,28

  int pidx[4];
#pragma unroll
  for (int rr = 0; rr < 4; rr++) {
    int gr = m0 + arow + rr * 32;
    if (MODE == 1) pidx[rr] = (gr < M) ? perm[gr] : -1;
    else           pidx[rr] = (gr < M) ? gr : -1;
  }

  for (int kt = 0; kt < K; kt += 32) {
    // stage A (fp32 -> bf16), 128 x 32
#pragma unroll
    for (int rr = 0; rr < 4; rr++) {
      int r = arow + rr * 32;
      float4 v = make_float4(0.f, 0.f, 0.f, 0.f);
      if (pidx[rr] >= 0) v = *(const float4*)(A + (size_t)pidx[rr] * lda + kt + acol);
      union { uint16_t h[4]; uint2 u; } p;
      p.h[0] = f2bf(v.x); p.h[1] = f2bf(v.y); p.h[2] = f2bf(v.z); p.h[3] = f2bf(v.w);
      *(uint2*)(Al + r * 32 + acol) = p.u;
    }
    // stage B (bf16 B^T layout [n][k]) : tile 128 x 32
#pragma unroll
    for (int ss = 0; ss < 2; ss++) {
      int j = tid + ss * 256;
      int row = j >> 2, kp = (j & 3) * 8;
      uint4 bv = *(const uint4*)(Bt + (size_t)(n0 + row) * K + kt + kp);
      *(uint4*)(Bl + row * 32 + kp) = bv;
    }
    __syncthreads();
    bf16x8 af[4], bfr[4];
#pragma unroll
    for (int i = 0; i < 4; i++)
      af[i] = *(const bf16x8*)(Al + (wr + 16 * i + lm) * 32 + lq * 8);
#pragma unroll
    for (int j = 0; j < 4; j++)
      bfr[j] = *(const bf16x8*)(Bl + (wc + 16 * j + lm) * 32 + lq * 8);
#pragma unroll
    for (int i = 0; i < 4; i++)
#pragma unroll
      for (int j = 0; j < 4; j++)
        acc[i][j] = __builtin_amdgcn_mfma_f32_16x16x32_bf16(af[i], bfr[j], acc[i][j], 0, 0, 0);
    __syncthreads();
  }

  const int cb0 = n0 + wc + lm;
  float bj[4];
#pragma unroll
  for (int j = 0; j < 4; j++) bj[j] = bias ? bias[cb0 + 16 * j] : 0.f;

  if (MODE == 0) {
    float s1l[4] = {0.f, 0.f, 0.f, 0.f}, s2l[4] = {0.f, 0.f, 0.f, 0.f};
#pragma unroll
    for (int i = 0; i < 4; i++) {
      int rbase = m0 + wr + 16 * i + lq * 4;
#pragma unroll
      for (int r = 0; r < 4; r++) {
        int row = rbase + r;
        if (row < M) {
#pragma unroll
          for (int j = 0; j < 4; j++) {
            float v = acc[i][j][r] + bj[j];
            C[(size_t)row * 256 + cb0 + 16 * j] = v;
            s1l[j] += v;
            s2l[j] += v * v;
          }
        }
      }
    }
    if (stats) {
      float* sb0 = (float*)Al;          // reuse LDS (k-loop is done)
      float* sb1 = sb0 + 128;
      __syncthreads();
      sb0[tid < 256 ? tid : 0] = 0.f;   // tid in [0,256): zero 256 floats
      __syncthreads();
#pragma unroll
      for (int j = 0; j < 4; j++) {
        int colloc = wc + lm + 16 * j;
        atomicAdd(&sb0[colloc], s1l[j]);
        atomicAdd(&sb1[colloc], s2l[j]);
      }
      __syncthreads();
      if (tid < 128) {
        atomicAdd(&stats[n0 + tid],       sb0[tid]);
        atomicAdd(&stats[256 + n0 + tid], sb1[tid]);
      }
    }
  } else {
#pragma unroll
    for (int i = 0; i < 4; i++) {
      int rbase = m0 + wr + 16 * i + lq * 4;
#pragma unroll
      for (int r = 0; r < 4; r++) {
        int row = rbase + r;
        if (row < M) {
          int sr = psrc[row];
          const float* xr = XT + (size_t)sr * 256;
#pragma unroll
          for (int j = 0; j < 4; j++) {
            float v = acc[i][j][r] + xr[cb0 + 16 * j] + bj[j];
            C[(size_t)row * 256 + cb0 + 16 * j] = fmaxf(v, 0.f);
          }
        }
      }
    }
  }
}

// ---------------- launch ----------------
extern "C" void kernel_launch(void* const* d_in, const int* in_sizes, int n_in,
                              void* d_out, int out_size, void* d_ws, size_t ws_size,
                              hipStream_t stream) {
  const float* x    = (const float*)d_in[0];
  const float* upA  = (const float*)d_in[1];
  const float* dnA  = (const float*)d_in[2];
  const float* bA   = (const float*)d_in[3];
  const float* Wmu  = (const float*)d_in[4];
  const float* bmu  = (const float*)d_in[5];
  const float* Wmd  = (const float*)d_in[6];
  const float* bmd  = (const float*)d_in[7];
  const float* W1[3] = {(const float*)d_in[8],  (const float*)d_in[16], (const float*)d_in[24]};
  const float* b1[3] = {(const float*)d_in[9],  (const float*)d_in[17], (const float*)d_in[25]};
  const float* g1[3] = {(const float*)d_in[10], (const float*)d_in[18], (const float*)d_in[26]};
  const float* c1[3] = {(const float*)d_in[11], (const float*)d_in[19], (const float*)d_in[27]};
  const float* W2[3] = {(const float*)d_in[12], (const float*)d_in[20], (const float*)d_in[28]};
  const float* b2[3] = {(const float*)d_in[13], (const float*)d_in[21], (const float*)d_in[29]};
  const float* g2[3] = {(const float*)d_in[14], (const float*)d_in[22], (const float*)d_in[30]};
  const float* c2[3] = {(const float*)d_in[15], (const float*)d_in[23], (const float*)d_in[31]};
  const float* Wc   = (const float*)d_in[32];
  const float* bc   = (const float*)d_in[33];
  const float* gc   = (const float*)d_in[34];
  const float* cc   = (const float*)d_in[35];
  const float* e1   = (const float*)d_in[36];
  const float* e2   = (const float*)d_in[37];
  const float* e3   = (const float*)d_in[38];
  const int* upI = (const int*)d_in[39];
  const int* dnI = (const int*)d_in[40];
  const int* bI  = (const int*)d_in[41];

  // ---------- workspace layout (floats) ----------
  float* base = (float*)d_ws;
  size_t o = 0;
  float* XU   = base + o; o += NM;                  // 10.24M
  float* XD   = base + o; o += NM;                  // 10.24M
  float* ACC0 = base + o; o += NM;
  float* ACC1 = base + o; o += NM;
  float* ACC2 = base + o; o += NM;
  float* POOL = base + o; o += (size_t)200000 * 256; // 51.2M floats
  float* CAT  = POOL;                                // 30.72M
  float* Y    = POOL + (size_t)NCELL * 768;          // 10.24M
  float* Z    = Y + NM;                              // 10.24M
  float* MSG  = POOL;                                // aliases CAT|Y|Z (edge phase only)
  float* STATS = base + o; o += 7 * 512;
  uint16_t* wb = (uint16_t*)(base + o); o += 600000; // bf16 weights (852k elems < 1.2M halves)
  uint16_t* WmuAt = wb;
  uint16_t* WmuBt = wb + 1 * 65536;
  uint16_t* WmdAt = wb + 2 * 65536;
  uint16_t* WmdBt = wb + 3 * 65536;
  uint16_t* W1t[3] = {wb + 4 * 65536, wb + 5 * 65536, wb + 6 * 65536};
  uint16_t* W2t[3] = {wb + 7 * 65536, wb + 8 * 65536, wb + 9 * 65536};
  uint16_t* Wct    = wb + 10 * 65536;               // 256 x 768
  int* ib = (int*)(base + o);
  int* offsU = ib;                 // 40001
  int* offsD = ib + 40001;
  int* offsB = ib + 80002;
  int* headU = ib + 120003;        // 40000 each (also the count array)
  int* headD = ib + 160003;
  int* headB = ib + 200003;
  int* permU = ib + 240003;        // 200000
  int* psrcU = ib + 440003;        // 200000
  int* permD = ib + 640003;
  int* psrcD = ib + 840003;
  int* permB = ib + 1040003;       // 120000
  int* psrcB = ib + 1160003;       // 120000

  float* ACCs[3] = {ACC0, ACC1, ACC2};

  hipMemsetAsync(STATS, 0, 7 * 512 * sizeof(float), stream);
  hipMemsetAsync(headU, 0, 3 * 40000 * sizeof(int), stream);  // headU/D/B contiguous

  // weights -> bf16 B^T
  WArgs wa;
  wa.src[0] = Wmu;               wa.dst[0] = WmuAt;  wa.K[0] = 256;
  wa.src[1] = Wmu + 256 * 256;   wa.dst[1] = WmuBt;  wa.K[1] = 256;
  wa.src[2] = Wmd;               wa.dst[2] = WmdAt;  wa.K[2] = 256;
  wa.src[3] = Wmd + 256 * 256;   wa.dst[3] = WmdBt;  wa.K[3] = 256;
  for (int t = 0; t < 3; t++) {
    wa.src[4 + 2 * t] = W1[t];   wa.dst[4 + 2 * t] = W1t[t]; wa.K[4 + 2 * t] = 256;
    wa.src[5 + 2 * t] = W2[t];   wa.dst[5 + 2 * t] = W2t[t]; wa.K[5 + 2 * t] = 256;
  }
  wa.src[10] = Wc; wa.dst[10] = Wct; wa.K[10] = 768;
  k_wconv<<<dim3(24, 8, 11), dim3(32, 8), 0, stream>>>(wa);

  // CSR build (targets are index[1] == ptr + E)
  k_count<<<(EUE + 255) / 256, 256, 0, stream>>>(upI + EUE, headU, EUE);
  k_count<<<(EDE + 255) / 256, 256, 0, stream>>>(dnI + EDE, headD, EDE);
  k_count<<<(EBE + 255) / 256, 256, 0, stream>>>(bI + EBE, headB, EBE);
  ScanArgs sa;
  sa.cnt[0] = headU; sa.offs[0] = offsU; sa.head[0] = headU;
  sa.cnt[1] = headD; sa.offs[1] = offsD; sa.head[1] = headD;
  sa.cnt[2] = headB; sa.offs[2] = offsB; sa.head[2] = headB;
  k_scan<<<3, 1024, 0, stream>>>(sa);
  k_fill<<<(EUE + 255) / 256, 256, 0, stream>>>(upI, upI + EUE, headU, permU, psrcU, EUE);
  k_fill<<<(EDE + 255) / 256, 256, 0, stream>>>(dnI, dnI + EDE, headD, permD, psrcD, EDE);
  k_fill<<<(EBE + 255) / 256, 256, 0, stream>>>(bI, bI + EBE, headB, permB, psrcB, EBE);

  const dim3 gN((NCELL + 127) / 128, 2);
  const dim3 gE((EUE + 127) / 128, 2);

  // XU = x @ Wmu[:256],  XD = x @ Wmd[:256]
  k_gemm<0><<<gN, 256, 0, stream>>>(x, 256, WmuAt, 256, nullptr, XU, nullptr,
                                    nullptr, nullptr, nullptr, NCELL);
  k_gemm<0><<<gN, 256, 0, stream>>>(x, 256, WmdAt, 256, nullptr, XD, nullptr,
                                    nullptr, nullptr, nullptr, NCELL);

  // edge up: GEMM (CSR order, relu+XU fused, contiguous store) -> segment sum -> ACC0
  k_gemm<1><<<gE, 256, 0, stream>>>(upA, 256, WmuBt, 256, bmu, MSG, nullptr,
                                    permU, psrcU, XU, EUE);
  k_segsum<<<NCELL, 64, 0, stream>>>(MSG, offsU, x, e1, ACC0);

  // edge down
  k_gemm<1><<<gE, 256, 0, stream>>>(dnA, 256, WmdBt, 256, bmd, MSG, nullptr,
                                    permD, psrcD, XD, EDE);
  k_segsum<<<NCELL, 64, 0, stream>>>(MSG, offsD, x, e2, ACC1);

  // boundary: gather (identity messages) -> ACC2
  k_bgather<<<NCELL, 64, 0, stream>>>(bA, offsB, psrcB, x, e3, ACC2);

  // three MLP branches (stats fused into GEMM epilogue)
  for (int t = 0; t < 3; t++) {
    float* S1 = STATS + 512 * (2 * t);
    float* S2 = STATS + 512 * (2 * t + 1);
    k_gemm<0><<<gN, 256, 0, stream>>>(ACCs[t], 256, W1t[t], 256, b1[t], Y, S1,
                                      nullptr, nullptr, nullptr, NCELL);
    k_bnrelu<<<10000, 256, 0, stream>>>(Y, S1, g1[t], c1[t], Z, 256);
    k_gemm<0><<<gN, 256, 0, stream>>>(Z, 256, W2t[t], 256, b2[t], Y, S2,
                                      nullptr, nullptr, nullptr, NCELL);
    k_bnrelu<<<10000, 256, 0, stream>>>(Y, S2, g2[t], c2[t], CAT + 256 * t, 768);
  }

  // final combine: Yc = CAT @ Wc + bc ; out = relu(BN(Yc))
  float* SC = STATS + 512 * 6;
  k_gemm<0><<<gN, 256, 0, stream>>>(CAT, 768, Wct, 768, bc, Y, SC,
                                    nullptr, nullptr, nullptr, NCELL);
  k_bnrelu<<<10000, 256, 0, stream>>>(Y, SC, gc, cc, (float*)d_out, 256);
}